// Round 1
// baseline (6713.915 us; speedup 1.0000x reference)
//
#include <hip/hip_runtime.h>
#include <hip/hip_bf16.h>
#include <stdint.h>

// MoE head: gate = softmax(relu(x@Wg1+bg1)@Wg2+bg2) top-2; experts dense.
// Expert path: bf16 MFMA GEMM with fused relu*We2 reduction epilogue.
// Gate path: 3-term bf16 split GEMM (fp32-class accuracy, needed for top-k
// to match the numpy reference) with fused relu*Wg2 logit epilogue.
// Finalize: reduce partials, top-2, renormalized softmax combine.

#define B_DIM  16384
#define H_DIM  4096
#define H2_DIM 2048
#define E_DIM  8

typedef __attribute__((ext_vector_type(8))) short short8;
typedef __attribute__((ext_vector_type(4))) float f32x4;

static __device__ __forceinline__ unsigned int bf16_rn(float f) {
    unsigned int u = __builtin_bit_cast(unsigned int, f);
    u += 0x7FFFu + ((u >> 16) & 1u);
    return u >> 16;
}
static __device__ __forceinline__ float bf16f(unsigned int h) {
    unsigned int u = h << 16;
    return __builtin_bit_cast(float, u);
}

// ---------------------------------------------------------------------------
// Expert GEMM: C[b, e*2048+d] = x[b,:] @ We1[e,:,d], epilogue
// epart[b][e][chunk] = sum_d relu(C + be1) * We2   (128-d chunks)
// grid: x = 128 col-blocks (e=nb>>4, chunk=nb&15), y = 128 row-blocks
// ---------------------------------------------------------------------------
__global__ __launch_bounds__(256, 2) void moe_expert_gemm(
    const float* __restrict__ x, const float* __restrict__ We1,
    const float* __restrict__ be1, const float* __restrict__ We2,
    float* __restrict__ epart)
{
    __shared__ short lA[128 * 64];
    __shared__ short lB[128 * 64];
    __shared__ float red[2][128];

    const int tid  = threadIdx.x;
    const int lane = tid & 63;
    const int wm   = (tid >> 6) >> 1;
    const int wn   = (tid >> 6) & 1;
    const int nb = blockIdx.x, bm = blockIdx.y;
    const int e = nb >> 4, chunk = nb & 15;
    const int dbase = chunk * 128;

    const float* Asrc = x + (size_t)bm * 128 * H_DIM;
    const float* Bsrc = We1 + (size_t)e * H_DIM * H2_DIM + dbase;

    f32x4 acc[4][4];
#pragma unroll
    for (int i = 0; i < 4; ++i)
#pragma unroll
        for (int j = 0; j < 4; ++j) acc[i][j] = (f32x4){0.f, 0.f, 0.f, 0.f};

    const int arow0 = tid >> 4, af4 = tid & 15;   // A stage: (row, float4-idx)
    const int bn = tid & 127, bkc0 = tid >> 7;    // B stage: (col n, k-chunk base)

    for (int k0 = 0; k0 < H_DIM; k0 += 64) {
        __syncthreads();
        // stage A: x rows -> lA[row][k] bf16, XOR-swizzled (T2)
#pragma unroll
        for (int j = 0; j < 8; ++j) {
            const int row = arow0 + j * 16;
            const float* p = Asrc + (size_t)row * H_DIM + k0 + af4 * 4;
            float a0 = p[0], a1 = p[1], a2 = p[2], a3 = p[3];
            uint2 w;
            w.x = bf16_rn(a0) | (bf16_rn(a1) << 16);
            w.y = bf16_rn(a2) | (bf16_rn(a3) << 16);
            const int byte = row * 128 + ((af4 * 8) ^ ((row & 7) << 4));
            *reinterpret_cast<uint2*>(reinterpret_cast<char*>(lA) + byte) = w;
        }
        // stage B transposed: We1[k][d] -> lB[n=d][k] bf16 (strided-coalesced gather)
#pragma unroll
        for (int j = 0; j < 4; ++j) {
            const int kc = bkc0 + 2 * j;
            const float* p = Bsrc + (size_t)(k0 + kc * 8) * H2_DIM + bn;
            uint4 w;
            w.x = bf16_rn(p[0])          | (bf16_rn(p[H2_DIM])     << 16);
            w.y = bf16_rn(p[2 * H2_DIM]) | (bf16_rn(p[3 * H2_DIM]) << 16);
            w.z = bf16_rn(p[4 * H2_DIM]) | (bf16_rn(p[5 * H2_DIM]) << 16);
            w.w = bf16_rn(p[6 * H2_DIM]) | (bf16_rn(p[7 * H2_DIM]) << 16);
            const int byte = bn * 128 + ((kc * 16) ^ ((bn & 7) << 4));
            *reinterpret_cast<uint4*>(reinterpret_cast<char*>(lB) + byte) = w;
        }
        __syncthreads();
#pragma unroll
        for (int kk = 0; kk < 2; ++kk) {
            const int kbyte = kk * 64 + ((lane >> 4) << 4);
            short8 af[4], bfr[4];
#pragma unroll
            for (int mi = 0; mi < 4; ++mi) {
                const int r = wm * 64 + mi * 16 + (lane & 15);
                af[mi] = *reinterpret_cast<const short8*>(
                    reinterpret_cast<const char*>(lA) + r * 128 + (kbyte ^ ((r & 7) << 4)));
            }
#pragma unroll
            for (int ni = 0; ni < 4; ++ni) {
                const int r = wn * 64 + ni * 16 + (lane & 15);
                bfr[ni] = *reinterpret_cast<const short8*>(
                    reinterpret_cast<const char*>(lB) + r * 128 + (kbyte ^ ((r & 7) << 4)));
            }
#pragma unroll
            for (int mi = 0; mi < 4; ++mi)
#pragma unroll
                for (int ni = 0; ni < 4; ++ni)
                    acc[mi][ni] = __builtin_amdgcn_mfma_f32_16x16x32_bf16(
                        af[mi], bfr[ni], acc[mi][ni], 0, 0, 0);
        }
    }

    // epilogue: relu(acc + be1) * We2, reduce over this block's 128 d-cols
    const int c = lane & 15, g = lane >> 4;
    float w2v[4], b1v[4];
#pragma unroll
    for (int ni = 0; ni < 4; ++ni) {
        const int d = dbase + wn * 64 + ni * 16 + c;
        b1v[ni] = be1[e * H2_DIM + d];
        w2v[ni] = We2[e * H2_DIM + d];
    }
#pragma unroll
    for (int mi = 0; mi < 4; ++mi) {
#pragma unroll
        for (int r = 0; r < 4; ++r) {
            float s = 0.f;
#pragma unroll
            for (int ni = 0; ni < 4; ++ni) {
                float v = acc[mi][ni][r] + b1v[ni];
                v = fmaxf(v, 0.f);
                s = fmaf(v, w2v[ni], s);
            }
            s += __shfl_xor(s, 1);
            s += __shfl_xor(s, 2);
            s += __shfl_xor(s, 4);
            s += __shfl_xor(s, 8);
            if (c == 0) red[wn][wm * 64 + mi * 16 + g * 4 + r] = s;
        }
    }
    __syncthreads();
    if (tid < 128) {
        const int b = bm * 128 + tid;
        epart[((size_t)b * E_DIM + e) * 16 + chunk] = red[0][tid] + red[1][tid];
    }
}

// ---------------------------------------------------------------------------
// Gate GEMM, 3-term bf16 split for ~fp32 accuracy (top-k must match ref).
// gpart[b][nb][e8] = sum_{d in chunk} relu(x@Wg1 + bg1) * Wg2[d][e8]
// grid: x = 16 col-blocks (d chunks of 128), y = 128 row-blocks
// ---------------------------------------------------------------------------
__global__ __launch_bounds__(256, 2) void moe_gate_gemm(
    const float* __restrict__ x, const float* __restrict__ Wg1,
    const float* __restrict__ bg1, const float* __restrict__ Wg2,
    float* __restrict__ gpart)
{
    __shared__ short lAh[128 * 64], lAl[128 * 64];
    __shared__ short lBh[128 * 64], lBl[128 * 64];
    __shared__ float lW2[128 * 8];
    __shared__ float gred[2][128][8];

    const int tid  = threadIdx.x;
    const int lane = tid & 63;
    const int wm = (tid >> 6) >> 1, wn = (tid >> 6) & 1;
    const int nb = blockIdx.x, bm = blockIdx.y;
    const int dbase = nb * 128;

    const float* Asrc = x + (size_t)bm * 128 * H_DIM;
    const float* Bsrc = Wg1 + dbase;

    {   // Wg2 slice [dbase..dbase+128) x 8 -> LDS
        const f32x4* s = reinterpret_cast<const f32x4*>(Wg2 + (size_t)dbase * 8);
        reinterpret_cast<f32x4*>(lW2)[tid] = s[tid];
    }

    f32x4 acc[4][4];
#pragma unroll
    for (int i = 0; i < 4; ++i)
#pragma unroll
        for (int j = 0; j < 4; ++j) acc[i][j] = (f32x4){0.f, 0.f, 0.f, 0.f};

    const int arow0 = tid >> 4, af4 = tid & 15;
    const int bn = tid & 127, bkc0 = tid >> 7;

    for (int k0 = 0; k0 < H_DIM; k0 += 64) {
        __syncthreads();
#pragma unroll
        for (int j = 0; j < 8; ++j) {
            const int row = arow0 + j * 16;
            const float* p = Asrc + (size_t)row * H_DIM + k0 + af4 * 4;
            float a[4] = {p[0], p[1], p[2], p[3]};
            unsigned int hb[4], lb[4];
#pragma unroll
            for (int q = 0; q < 4; ++q) {
                hb[q] = bf16_rn(a[q]);
                lb[q] = bf16_rn(a[q] - bf16f(hb[q]));
            }
            const int byte = row * 128 + ((af4 * 8) ^ ((row & 7) << 4));
            *reinterpret_cast<uint2*>(reinterpret_cast<char*>(lAh) + byte) =
                make_uint2(hb[0] | (hb[1] << 16), hb[2] | (hb[3] << 16));
            *reinterpret_cast<uint2*>(reinterpret_cast<char*>(lAl) + byte) =
                make_uint2(lb[0] | (lb[1] << 16), lb[2] | (lb[3] << 16));
        }
#pragma unroll
        for (int j = 0; j < 4; ++j) {
            const int kc = bkc0 + 2 * j;
            const float* p = Bsrc + (size_t)(k0 + kc * 8) * H2_DIM + bn;
            unsigned int hb[8], lb[8];
#pragma unroll
            for (int q = 0; q < 8; ++q) {
                float v = p[(size_t)q * H2_DIM];
                hb[q] = bf16_rn(v);
                lb[q] = bf16_rn(v - bf16f(hb[q]));
            }
            const int byte = bn * 128 + ((kc * 16) ^ ((bn & 7) << 4));
            *reinterpret_cast<uint4*>(reinterpret_cast<char*>(lBh) + byte) =
                make_uint4(hb[0] | (hb[1] << 16), hb[2] | (hb[3] << 16),
                           hb[4] | (hb[5] << 16), hb[6] | (hb[7] << 16));
            *reinterpret_cast<uint4*>(reinterpret_cast<char*>(lBl) + byte) =
                make_uint4(lb[0] | (lb[1] << 16), lb[2] | (lb[3] << 16),
                           lb[4] | (lb[5] << 16), lb[6] | (lb[7] << 16));
        }
        __syncthreads();
#pragma unroll
        for (int kk = 0; kk < 2; ++kk) {
            const int kbyte = kk * 64 + ((lane >> 4) << 4);
            short8 ah[4], al[4], bh[4], bl[4];
#pragma unroll
            for (int mi = 0; mi < 4; ++mi) {
                const int r = wm * 64 + mi * 16 + (lane & 15);
                const int off = r * 128 + (kbyte ^ ((r & 7) << 4));
                ah[mi] = *reinterpret_cast<const short8*>(reinterpret_cast<const char*>(lAh) + off);
                al[mi] = *reinterpret_cast<const short8*>(reinterpret_cast<const char*>(lAl) + off);
            }
#pragma unroll
            for (int ni = 0; ni < 4; ++ni) {
                const int r = wn * 64 + ni * 16 + (lane & 15);
                const int off = r * 128 + (kbyte ^ ((r & 7) << 4));
                bh[ni] = *reinterpret_cast<const short8*>(reinterpret_cast<const char*>(lBh) + off);
                bl[ni] = *reinterpret_cast<const short8*>(reinterpret_cast<const char*>(lBl) + off);
            }
#pragma unroll
            for (int mi = 0; mi < 4; ++mi)
#pragma unroll
                for (int ni = 0; ni < 4; ++ni) {
                    acc[mi][ni] = __builtin_amdgcn_mfma_f32_16x16x32_bf16(ah[mi], bh[ni], acc[mi][ni], 0, 0, 0);
                    acc[mi][ni] = __builtin_amdgcn_mfma_f32_16x16x32_bf16(ah[mi], bl[ni], acc[mi][ni], 0, 0, 0);
                    acc[mi][ni] = __builtin_amdgcn_mfma_f32_16x16x32_bf16(al[mi], bh[ni], acc[mi][ni], 0, 0, 0);
                }
        }
    }

    // epilogue: relu(acc + bg1) * Wg2[:,e8], reduce over 128 d-cols
    const int c = lane & 15, g = lane >> 4;
    float bgv[4];
#pragma unroll
    for (int ni = 0; ni < 4; ++ni) bgv[ni] = bg1[dbase + wn * 64 + ni * 16 + c];
#pragma unroll
    for (int mi = 0; mi < 4; ++mi) {
#pragma unroll
        for (int r = 0; r < 4; ++r) {
            float gv[4];
#pragma unroll
            for (int ni = 0; ni < 4; ++ni)
                gv[ni] = fmaxf(acc[mi][ni][r] + bgv[ni], 0.f);
#pragma unroll
            for (int e8 = 0; e8 < 8; ++e8) {
                float t = 0.f;
#pragma unroll
                for (int ni = 0; ni < 4; ++ni)
                    t = fmaf(gv[ni], lW2[(wn * 64 + ni * 16 + c) * 8 + e8], t);
                t += __shfl_xor(t, 1);
                t += __shfl_xor(t, 2);
                t += __shfl_xor(t, 4);
                t += __shfl_xor(t, 8);
                if (c == e8) gred[wn][wm * 64 + mi * 16 + g * 4 + r][e8] = t;
            }
        }
    }
    __syncthreads();
    {
        const int row = tid & 127;
        const int ebase = (tid >> 7) * 4;
        const int b = bm * 128 + row;
#pragma unroll
        for (int i = 0; i < 4; ++i) {
            const int e8 = ebase + i;
            gpart[(size_t)b * 128 + nb * 8 + e8] = gred[0][row][e8] + gred[1][row][e8];
        }
    }
}

// ---------------------------------------------------------------------------
// Finalize: reduce partials, softmax top-2 (renormalized), combine.
// ---------------------------------------------------------------------------
__global__ __launch_bounds__(256) void moe_finalize(
    const float* __restrict__ gpart, const float* __restrict__ epart,
    const float* __restrict__ bg2, const float* __restrict__ be2,
    float* __restrict__ out)
{
    const int b = blockIdx.x * 256 + threadIdx.x;
    float logit[8];
#pragma unroll
    for (int e = 0; e < 8; ++e) logit[e] = bg2[e];
    const float* gp = gpart + (size_t)b * 128;
#pragma unroll
    for (int cN = 0; cN < 16; ++cN)
#pragma unroll
        for (int e = 0; e < 8; ++e) logit[e] += gp[cN * 8 + e];

    float eo[8];
    const float* ep = epart + (size_t)b * 128;
#pragma unroll
    for (int e = 0; e < 8; ++e) {
        float s = be2[e];
#pragma unroll
        for (int cN = 0; cN < 16; ++cN) s += ep[e * 16 + cN];
        eo[e] = s;
    }

    // top-2 with lax.top_k tie semantics (strict >, keep lowest index)
    int i1 = 0; float m1 = logit[0];
#pragma unroll
    for (int e = 1; e < 8; ++e) if (logit[e] > m1) { m1 = logit[e]; i1 = e; }
    int i2 = -1; float m2 = -3.4e38f;
#pragma unroll
    for (int e = 0; e < 8; ++e) if (e != i1 && logit[e] > m2) { m2 = logit[e]; i2 = e; }

    // top_p renorm: full softmax denominator cancels
    const float w2 = expf(m2 - m1);
    out[b] = (eo[i1] + w2 * eo[i2]) / (1.f + w2);
}

// ---------------------------------------------------------------------------
extern "C" void kernel_launch(void* const* d_in, const int* in_sizes, int n_in,
                              void* d_out, int out_size, void* d_ws, size_t ws_size,
                              hipStream_t stream) {
    (void)in_sizes; (void)n_in; (void)out_size; (void)ws_size;
    const float* x   = (const float*)d_in[0];
    const float* We1 = (const float*)d_in[1];
    const float* be1 = (const float*)d_in[2];
    const float* We2 = (const float*)d_in[3];
    const float* be2 = (const float*)d_in[4];
    const float* Wg1 = (const float*)d_in[5];
    const float* bg1 = (const float*)d_in[6];
    const float* Wg2 = (const float*)d_in[7];
    const float* bg2 = (const float*)d_in[8];
    float* out = (float*)d_out;

    float* gpart = (float*)d_ws;                          // [B][16][8]  = 8 MB
    float* epart = gpart + (size_t)B_DIM * 128;           // [B][8][16]  = 8 MB

    moe_gate_gemm<<<dim3(16, 128), 256, 0, stream>>>(x, Wg1, bg1, Wg2, gpart);
    moe_expert_gemm<<<dim3(128, 128), 256, 0, stream>>>(x, We1, be1, We2, epart);
    moe_finalize<<<64, 256, 0, stream>>>(gpart, epart, bg2, be2, out);
}

// Round 2
// 3287.000 us; speedup vs baseline: 2.0426x; 2.0426x over previous
//
#include <hip/hip_runtime.h>
#include <hip/hip_bf16.h>
#include <stdint.h>

// MoE head: gate = softmax(relu(x@Wg1+bg1)@Wg2+bg2) top-2; experts dense.
// Expert path: prepass-converted bf16 operands (x -> bf16, We1 -> bf16
// transposed [e][d][h]), then m97-style MFMA GEMM with global_load_lds
// (XOR swizzle baked into per-lane global source address) and fused
// relu*We2 reduction epilogue.
// Gate path: 3-term bf16 split GEMM (fp32-class accuracy for top-k).
// Finalize: reduce partials, top-2, renormalized softmax combine.

#define B_DIM  16384
#define H_DIM  4096
#define H2_DIM 2048
#define E_DIM  8

typedef __attribute__((ext_vector_type(8))) short short8;
typedef __attribute__((ext_vector_type(4))) float f32x4;

static __device__ __forceinline__ unsigned int bf16_rn(float f) {
    unsigned int u = __builtin_bit_cast(unsigned int, f);
    u += 0x7FFFu + ((u >> 16) & 1u);
    return u >> 16;
}
static __device__ __forceinline__ float bf16f(unsigned int h) {
    unsigned int u = h << 16;
    return __builtin_bit_cast(float, u);
}

static __device__ __forceinline__ void gload_lds16(const void* g, void* l) {
    __builtin_amdgcn_global_load_lds(
        (const __attribute__((address_space(1))) unsigned int*)g,
        (__attribute__((address_space(3))) unsigned int*)l,
        16, 0, 0);
}

// ---------------------------------------------------------------------------
// Prepass 1: x fp32 -> bf16 (RNE), linear layout.
// ---------------------------------------------------------------------------
__global__ __launch_bounds__(256) void convert_x_bf16(
    const float* __restrict__ x, unsigned short* __restrict__ xb)
{
    const size_t n8 = (size_t)B_DIM * H_DIM / 8;
    for (size_t i = (size_t)blockIdx.x * 256 + threadIdx.x; i < n8;
         i += (size_t)gridDim.x * 256) {
        const f32x4* p = reinterpret_cast<const f32x4*>(x) + 2 * i;
        f32x4 a = p[0], b = p[1];
        uint4 o;
        o.x = bf16_rn(a[0]) | (bf16_rn(a[1]) << 16);
        o.y = bf16_rn(a[2]) | (bf16_rn(a[3]) << 16);
        o.z = bf16_rn(b[0]) | (bf16_rn(b[1]) << 16);
        o.w = bf16_rn(b[2]) | (bf16_rn(b[3]) << 16);
        reinterpret_cast<uint4*>(xb)[i] = o;
    }
}

// ---------------------------------------------------------------------------
// Prepass 2: We1[e][h][d] fp32 -> w1t[e][d][h] bf16 (64x64 LDS tile transpose)
// ---------------------------------------------------------------------------
__global__ __launch_bounds__(256) void transpose_We1_bf16(
    const float* __restrict__ We1, unsigned short* __restrict__ w1t)
{
    __shared__ unsigned short t[64 * 66];
    const int tid = threadIdx.x;
    const int h0 = blockIdx.x * 64, d0 = blockIdx.y * 64;
    const int e = blockIdx.z;
    const float* src = We1 + ((size_t)e * H_DIM + h0) * H2_DIM + d0;
#pragma unroll
    for (int j = 0; j < 16; ++j) {
        const int row = (tid >> 6) + 4 * j;   // h_local
        const int col = tid & 63;             // d_local
        t[row * 66 + col] = (unsigned short)bf16_rn(src[(size_t)row * H2_DIM + col]);
    }
    __syncthreads();
    unsigned int* dst = reinterpret_cast<unsigned int*>(
        w1t + ((size_t)e * H2_DIM + d0) * H_DIM + h0);
#pragma unroll
    for (int j = 0; j < 8; ++j) {
        const int drow = (tid >> 5) + 8 * j;  // d_local
        const int hp = tid & 31;              // h pair index
        unsigned int v = (unsigned int)t[(2 * hp) * 66 + drow]
                       | ((unsigned int)t[(2 * hp + 1) * 66 + drow] << 16);
        dst[(size_t)drow * (H_DIM / 2) + hp] = v;
    }
}

// ---------------------------------------------------------------------------
// Expert GEMM (fast path): bf16 operands, global_load_lds staging with the
// st-XOR swizzle applied to the SOURCE address (LDS dest linear), swizzled
// ds_read_b128 fragments (identical to verified round-1 read pattern).
// epart[b][e][chunk] = sum_{d in 128-chunk} relu(x@We1 + be1) * We2
// ---------------------------------------------------------------------------
__global__ __launch_bounds__(256, 2) void moe_expert_gemm_bf16(
    const unsigned short* __restrict__ xb, const unsigned short* __restrict__ w1t,
    const float* __restrict__ be1, const float* __restrict__ We2,
    float* __restrict__ epart)
{
    __shared__ short lA[128 * 64];
    __shared__ short lB[128 * 64];
    __shared__ float red[2][128];

    const int tid  = threadIdx.x;
    const int lane = tid & 63;
    const int w    = tid >> 6;
    const int wm = w >> 1, wn = w & 1;
    const int nb = blockIdx.x, bm = blockIdx.y;
    const int e = nb >> 4, chunk = nb & 15;
    const int dbase = chunk * 128;

    const char* Abase = (const char*)(xb + (size_t)bm * 128 * H_DIM);
    const char* Bbase = (const char*)(w1t + ((size_t)e * H2_DIM + dbase) * H_DIM);

    f32x4 acc[4][4];
#pragma unroll
    for (int i = 0; i < 4; ++i)
#pragma unroll
        for (int j = 0; j < 4; ++j) acc[i][j] = (f32x4){0.f, 0.f, 0.f, 0.f};

    // staging map: 16B chunk c = (i*4+w)*64 + lane; LDS byte = c*16 (linear);
    // row = c>>3; source k-byte = ((c&7)*16) ^ ((row&7)<<4)  [inverse swizzle]
    int rowS[4], koffS[4], ldsoff[4];
#pragma unroll
    for (int i = 0; i < 4; ++i) {
        const int c = (i * 4 + w) * 64 + lane;
        rowS[i]   = c >> 3;
        koffS[i]  = ((c & 7) << 4) ^ ((rowS[i] & 7) << 4);
        ldsoff[i] = (i * 4 + w) << 10;   // wave-uniform chunk base (bytes)
    }

    for (int k0 = 0; k0 < H_DIM; k0 += 64) {
        __syncthreads();
#pragma unroll
        for (int i = 0; i < 4; ++i) {
            const size_t rb = ((size_t)rowS[i] * H_DIM + k0) * 2 + koffS[i];
            gload_lds16(Abase + rb, (char*)lA + ldsoff[i]);
            gload_lds16(Bbase + rb, (char*)lB + ldsoff[i]);
        }
        __syncthreads();
#pragma unroll
        for (int kk = 0; kk < 2; ++kk) {
            const int kbyte = kk * 64 + ((lane >> 4) << 4);
            short8 af[4], bfr[4];
#pragma unroll
            for (int mi = 0; mi < 4; ++mi) {
                const int r = wm * 64 + mi * 16 + (lane & 15);
                af[mi] = *reinterpret_cast<const short8*>(
                    reinterpret_cast<const char*>(lA) + r * 128 + (kbyte ^ ((r & 7) << 4)));
            }
#pragma unroll
            for (int ni = 0; ni < 4; ++ni) {
                const int r = wn * 64 + ni * 16 + (lane & 15);
                bfr[ni] = *reinterpret_cast<const short8*>(
                    reinterpret_cast<const char*>(lB) + r * 128 + (kbyte ^ ((r & 7) << 4)));
            }
#pragma unroll
            for (int mi = 0; mi < 4; ++mi)
#pragma unroll
                for (int ni = 0; ni < 4; ++ni)
                    acc[mi][ni] = __builtin_amdgcn_mfma_f32_16x16x32_bf16(
                        af[mi], bfr[ni], acc[mi][ni], 0, 0, 0);
        }
    }

    const int c = lane & 15, g = lane >> 4;
    float w2v[4], b1v[4];
#pragma unroll
    for (int ni = 0; ni < 4; ++ni) {
        const int d = dbase + wn * 64 + ni * 16 + c;
        b1v[ni] = be1[e * H2_DIM + d];
        w2v[ni] = We2[e * H2_DIM + d];
    }
#pragma unroll
    for (int mi = 0; mi < 4; ++mi) {
#pragma unroll
        for (int r = 0; r < 4; ++r) {
            float s = 0.f;
#pragma unroll
            for (int ni = 0; ni < 4; ++ni) {
                float v = acc[mi][ni][r] + b1v[ni];
                v = fmaxf(v, 0.f);
                s = fmaf(v, w2v[ni], s);
            }
            s += __shfl_xor(s, 1);
            s += __shfl_xor(s, 2);
            s += __shfl_xor(s, 4);
            s += __shfl_xor(s, 8);
            if (c == 0) red[wn][wm * 64 + mi * 16 + g * 4 + r] = s;
        }
    }
    __syncthreads();
    if (tid < 128) {
        const int b = bm * 128 + tid;
        epart[((size_t)b * E_DIM + e) * 16 + chunk] = red[0][tid] + red[1][tid];
    }
}

// ---------------------------------------------------------------------------
// Expert GEMM (fallback, fp32 in-kernel conversion) — round-1 verified.
// ---------------------------------------------------------------------------
__global__ __launch_bounds__(256, 2) void moe_expert_gemm(
    const float* __restrict__ x, const float* __restrict__ We1,
    const float* __restrict__ be1, const float* __restrict__ We2,
    float* __restrict__ epart)
{
    __shared__ short lA[128 * 64];
    __shared__ short lB[128 * 64];
    __shared__ float red[2][128];

    const int tid  = threadIdx.x;
    const int lane = tid & 63;
    const int wm   = (tid >> 6) >> 1;
    const int wn   = (tid >> 6) & 1;
    const int nb = blockIdx.x, bm = blockIdx.y;
    const int e = nb >> 4, chunk = nb & 15;
    const int dbase = chunk * 128;

    const float* Asrc = x + (size_t)bm * 128 * H_DIM;
    const float* Bsrc = We1 + (size_t)e * H_DIM * H2_DIM + dbase;

    f32x4 acc[4][4];
#pragma unroll
    for (int i = 0; i < 4; ++i)
#pragma unroll
        for (int j = 0; j < 4; ++j) acc[i][j] = (f32x4){0.f, 0.f, 0.f, 0.f};

    const int arow0 = tid >> 4, af4 = tid & 15;
    const int bn = tid & 127, bkc0 = tid >> 7;

    for (int k0 = 0; k0 < H_DIM; k0 += 64) {
        __syncthreads();
#pragma unroll
        for (int j = 0; j < 8; ++j) {
            const int row = arow0 + j * 16;
            const float* p = Asrc + (size_t)row * H_DIM + k0 + af4 * 4;
            float a0 = p[0], a1 = p[1], a2 = p[2], a3 = p[3];
            uint2 wv;
            wv.x = bf16_rn(a0) | (bf16_rn(a1) << 16);
            wv.y = bf16_rn(a2) | (bf16_rn(a3) << 16);
            const int byte = row * 128 + ((af4 * 8) ^ ((row & 7) << 4));
            *reinterpret_cast<uint2*>(reinterpret_cast<char*>(lA) + byte) = wv;
        }
#pragma unroll
        for (int j = 0; j < 4; ++j) {
            const int kc = bkc0 + 2 * j;
            const float* p = Bsrc + (size_t)(k0 + kc * 8) * H2_DIM + bn;
            uint4 wv;
            wv.x = bf16_rn(p[0])          | (bf16_rn(p[H2_DIM])     << 16);
            wv.y = bf16_rn(p[2 * H2_DIM]) | (bf16_rn(p[3 * H2_DIM]) << 16);
            wv.z = bf16_rn(p[4 * H2_DIM]) | (bf16_rn(p[5 * H2_DIM]) << 16);
            wv.w = bf16_rn(p[6 * H2_DIM]) | (bf16_rn(p[7 * H2_DIM]) << 16);
            const int byte = bn * 128 + ((kc * 16) ^ ((bn & 7) << 4));
            *reinterpret_cast<uint4*>(reinterpret_cast<char*>(lB) + byte) = wv;
        }
        __syncthreads();
#pragma unroll
        for (int kk = 0; kk < 2; ++kk) {
            const int kbyte = kk * 64 + ((lane >> 4) << 4);
            short8 af[4], bfr[4];
#pragma unroll
            for (int mi = 0; mi < 4; ++mi) {
                const int r = wm * 64 + mi * 16 + (lane & 15);
                af[mi] = *reinterpret_cast<const short8*>(
                    reinterpret_cast<const char*>(lA) + r * 128 + (kbyte ^ ((r & 7) << 4)));
            }
#pragma unroll
            for (int ni = 0; ni < 4; ++ni) {
                const int r = wn * 64 + ni * 16 + (lane & 15);
                bfr[ni] = *reinterpret_cast<const short8*>(
                    reinterpret_cast<const char*>(lB) + r * 128 + (kbyte ^ ((r & 7) << 4)));
            }
#pragma unroll
            for (int mi = 0; mi < 4; ++mi)
#pragma unroll
                for (int ni = 0; ni < 4; ++ni)
                    acc[mi][ni] = __builtin_amdgcn_mfma_f32_16x16x32_bf16(
                        af[mi], bfr[ni], acc[mi][ni], 0, 0, 0);
        }
    }

    const int c = lane & 15, g = lane >> 4;
    float w2v[4], b1v[4];
#pragma unroll
    for (int ni = 0; ni < 4; ++ni) {
        const int d = dbase + wn * 64 + ni * 16 + c;
        b1v[ni] = be1[e * H2_DIM + d];
        w2v[ni] = We2[e * H2_DIM + d];
    }
#pragma unroll
    for (int mi = 0; mi < 4; ++mi) {
#pragma unroll
        for (int r = 0; r < 4; ++r) {
            float s = 0.f;
#pragma unroll
            for (int ni = 0; ni < 4; ++ni) {
                float v = acc[mi][ni][r] + b1v[ni];
                v = fmaxf(v, 0.f);
                s = fmaf(v, w2v[ni], s);
            }
            s += __shfl_xor(s, 1);
            s += __shfl_xor(s, 2);
            s += __shfl_xor(s, 4);
            s += __shfl_xor(s, 8);
            if (c == 0) red[wn][wm * 64 + mi * 16 + g * 4 + r] = s;
        }
    }
    __syncthreads();
    if (tid < 128) {
        const int b = bm * 128 + tid;
        epart[((size_t)b * E_DIM + e) * 16 + chunk] = red[0][tid] + red[1][tid];
    }
}

// ---------------------------------------------------------------------------
// Gate GEMM, 3-term bf16 split for ~fp32 accuracy (top-k must match ref).
// ---------------------------------------------------------------------------
__global__ __launch_bounds__(256, 2) void moe_gate_gemm(
    const float* __restrict__ x, const float* __restrict__ Wg1,
    const float* __restrict__ bg1, const float* __restrict__ Wg2,
    float* __restrict__ gpart)
{
    __shared__ short lAh[128 * 64], lAl[128 * 64];
    __shared__ short lBh[128 * 64], lBl[128 * 64];
    __shared__ float lW2[128 * 8];
    __shared__ float gred[2][128][8];

    const int tid  = threadIdx.x;
    const int lane = tid & 63;
    const int wm = (tid >> 6) >> 1, wn = (tid >> 6) & 1;
    const int nb = blockIdx.x, bm = blockIdx.y;
    const int dbase = nb * 128;

    const float* Asrc = x + (size_t)bm * 128 * H_DIM;
    const float* Bsrc = Wg1 + dbase;

    {
        const f32x4* s = reinterpret_cast<const f32x4*>(Wg2 + (size_t)dbase * 8);
        reinterpret_cast<f32x4*>(lW2)[tid] = s[tid];
    }

    f32x4 acc[4][4];
#pragma unroll
    for (int i = 0; i < 4; ++i)
#pragma unroll
        for (int j = 0; j < 4; ++j) acc[i][j] = (f32x4){0.f, 0.f, 0.f, 0.f};

    const int arow0 = tid >> 4, af4 = tid & 15;
    const int bn = tid & 127, bkc0 = tid >> 7;

    for (int k0 = 0; k0 < H_DIM; k0 += 64) {
        __syncthreads();
#pragma unroll
        for (int j = 0; j < 8; ++j) {
            const int row = arow0 + j * 16;
            const float* p = Asrc + (size_t)row * H_DIM + k0 + af4 * 4;
            float a[4] = {p[0], p[1], p[2], p[3]};
            unsigned int hb[4], lb[4];
#pragma unroll
            for (int q = 0; q < 4; ++q) {
                hb[q] = bf16_rn(a[q]);
                lb[q] = bf16_rn(a[q] - bf16f(hb[q]));
            }
            const int byte = row * 128 + ((af4 * 8) ^ ((row & 7) << 4));
            *reinterpret_cast<uint2*>(reinterpret_cast<char*>(lAh) + byte) =
                make_uint2(hb[0] | (hb[1] << 16), hb[2] | (hb[3] << 16));
            *reinterpret_cast<uint2*>(reinterpret_cast<char*>(lAl) + byte) =
                make_uint2(lb[0] | (lb[1] << 16), lb[2] | (lb[3] << 16));
        }
#pragma unroll
        for (int j = 0; j < 4; ++j) {
            const int kc = bkc0 + 2 * j;
            const float* p = Bsrc + (size_t)(k0 + kc * 8) * H2_DIM + bn;
            unsigned int hb[8], lb[8];
#pragma unroll
            for (int q = 0; q < 8; ++q) {
                float v = p[(size_t)q * H2_DIM];
                hb[q] = bf16_rn(v);
                lb[q] = bf16_rn(v - bf16f(hb[q]));
            }
            const int byte = bn * 128 + ((kc * 16) ^ ((bn & 7) << 4));
            *reinterpret_cast<uint4*>(reinterpret_cast<char*>(lBh) + byte) =
                make_uint4(hb[0] | (hb[1] << 16), hb[2] | (hb[3] << 16),
                           hb[4] | (hb[5] << 16), hb[6] | (hb[7] << 16));
            *reinterpret_cast<uint4*>(reinterpret_cast<char*>(lBl) + byte) =
                make_uint4(lb[0] | (lb[1] << 16), lb[2] | (lb[3] << 16),
                           lb[4] | (lb[5] << 16), lb[6] | (lb[7] << 16));
        }
        __syncthreads();
#pragma unroll
        for (int kk = 0; kk < 2; ++kk) {
            const int kbyte = kk * 64 + ((lane >> 4) << 4);
            short8 ah[4], al[4], bh[4], bl[4];
#pragma unroll
            for (int mi = 0; mi < 4; ++mi) {
                const int r = wm * 64 + mi * 16 + (lane & 15);
                const int off = r * 128 + (kbyte ^ ((r & 7) << 4));
                ah[mi] = *reinterpret_cast<const short8*>(reinterpret_cast<const char*>(lAh) + off);
                al[mi] = *reinterpret_cast<const short8*>(reinterpret_cast<const char*>(lAl) + off);
            }
#pragma unroll
            for (int ni = 0; ni < 4; ++ni) {
                const int r = wn * 64 + ni * 16 + (lane & 15);
                const int off = r * 128 + (kbyte ^ ((r & 7) << 4));
                bh[ni] = *reinterpret_cast<const short8*>(reinterpret_cast<const char*>(lBh) + off);
                bl[ni] = *reinterpret_cast<const short8*>(reinterpret_cast<const char*>(lBl) + off);
            }
#pragma unroll
            for (int mi = 0; mi < 4; ++mi)
#pragma unroll
                for (int ni = 0; ni < 4; ++ni) {
                    acc[mi][ni] = __builtin_amdgcn_mfma_f32_16x16x32_bf16(ah[mi], bh[ni], acc[mi][ni], 0, 0, 0);
                    acc[mi][ni] = __builtin_amdgcn_mfma_f32_16x16x32_bf16(ah[mi], bl[ni], acc[mi][ni], 0, 0, 0);
                    acc[mi][ni] = __builtin_amdgcn_mfma_f32_16x16x32_bf16(al[mi], bh[ni], acc[mi][ni], 0, 0, 0);
                }
        }
    }

    const int c = lane & 15, g = lane >> 4;
    float bgv[4];
#pragma unroll
    for (int ni = 0; ni < 4; ++ni) bgv[ni] = bg1[dbase + wn * 64 + ni * 16 + c];
#pragma unroll
    for (int mi = 0; mi < 4; ++mi) {
#pragma unroll
        for (int r = 0; r < 4; ++r) {
            float gv[4];
#pragma unroll
            for (int ni = 0; ni < 4; ++ni)
                gv[ni] = fmaxf(acc[mi][ni][r] + bgv[ni], 0.f);
#pragma unroll
            for (int e8 = 0; e8 < 8; ++e8) {
                float t = 0.f;
#pragma unroll
                for (int ni = 0; ni < 4; ++ni)
                    t = fmaf(gv[ni], lW2[(wn * 64 + ni * 16 + c) * 8 + e8], t);
                t += __shfl_xor(t, 1);
                t += __shfl_xor(t, 2);
                t += __shfl_xor(t, 4);
                t += __shfl_xor(t, 8);
                if (c == e8) gred[wn][wm * 64 + mi * 16 + g * 4 + r][e8] = t;
            }
        }
    }
    __syncthreads();
    {
        const int row = tid & 127;
        const int ebase = (tid >> 7) * 4;
        const int b = bm * 128 + row;
#pragma unroll
        for (int i = 0; i < 4; ++i) {
            const int e8 = ebase + i;
            gpart[(size_t)b * 128 + nb * 8 + e8] = gred[0][row][e8] + gred[1][row][e8];
        }
    }
}

// ---------------------------------------------------------------------------
// Finalize: reduce partials, softmax top-2 (renormalized), combine.
// ---------------------------------------------------------------------------
__global__ __launch_bounds__(256) void moe_finalize(
    const float* __restrict__ gpart, const float* __restrict__ epart,
    const float* __restrict__ bg2, const float* __restrict__ be2,
    float* __restrict__ out)
{
    const int b = blockIdx.x * 256 + threadIdx.x;
    float logit[8];
#pragma unroll
    for (int e = 0; e < 8; ++e) logit[e] = bg2[e];
    const float* gp = gpart + (size_t)b * 128;
#pragma unroll
    for (int cN = 0; cN < 16; ++cN)
#pragma unroll
        for (int e = 0; e < 8; ++e) logit[e] += gp[cN * 8 + e];

    float eo[8];
    const float* ep = epart + (size_t)b * 128;
#pragma unroll
    for (int e = 0; e < 8; ++e) {
        float s = be2[e];
#pragma unroll
        for (int cN = 0; cN < 16; ++cN) s += ep[e * 16 + cN];
        eo[e] = s;
    }

    int i1 = 0; float m1 = logit[0];
#pragma unroll
    for (int e = 1; e < 8; ++e) if (logit[e] > m1) { m1 = logit[e]; i1 = e; }
    int i2 = -1; float m2 = -3.4e38f;
#pragma unroll
    for (int e = 0; e < 8; ++e) if (e != i1 && logit[e] > m2) { m2 = logit[e]; i2 = e; }

    const float w2 = expf(m2 - m1);
    out[b] = (eo[i1] + w2 * eo[i2]) / (1.f + w2);
}

// ---------------------------------------------------------------------------
extern "C" void kernel_launch(void* const* d_in, const int* in_sizes, int n_in,
                              void* d_out, int out_size, void* d_ws, size_t ws_size,
                              hipStream_t stream) {
    (void)in_sizes; (void)n_in; (void)out_size;
    const float* x   = (const float*)d_in[0];
    const float* We1 = (const float*)d_in[1];
    const float* be1 = (const float*)d_in[2];
    const float* We2 = (const float*)d_in[3];
    const float* be2 = (const float*)d_in[4];
    const float* Wg1 = (const float*)d_in[5];
    const float* bg1 = (const float*)d_in[6];
    const float* Wg2 = (const float*)d_in[7];
    const float* bg2 = (const float*)d_in[8];
    float* out = (float*)d_out;

    char* ws = (char*)d_ws;
    size_t off = 0;
    float* gpart = (float*)(ws + off);           off += (size_t)B_DIM * 128 * 4;   // 8 MB
    float* epart = (float*)(ws + off);           off += (size_t)B_DIM * 128 * 4;   // 8 MB
    unsigned short* xb  = (unsigned short*)(ws + off); off += (size_t)B_DIM * H_DIM * 2;          // 128 MB
    unsigned short* w1t = (unsigned short*)(ws + off); off += (size_t)E_DIM * H2_DIM * H_DIM * 2; // 128 MB
    const size_t NEED = off;

    if (ws_size >= NEED) {
        convert_x_bf16<<<4096, 256, 0, stream>>>(x, xb);
        transpose_We1_bf16<<<dim3(64, 32, 8), 256, 0, stream>>>(We1, w1t);
        moe_expert_gemm_bf16<<<dim3(128, 128), 256, 0, stream>>>(xb, w1t, be1, We2, epart);
    } else {
        moe_expert_gemm<<<dim3(128, 128), 256, 0, stream>>>(x, We1, be1, We2, epart);
    }
    moe_gate_gemm<<<dim3(16, 128), 256, 0, stream>>>(x, Wg1, bg1, Wg2, gpart);
    moe_finalize<<<64, 256, 0, stream>>>(gpart, epart, bg2, be2, out);
}